// Round 8
// baseline (553.949 us; speedup 1.0000x reference)
//
#include <hip/hip_runtime.h>

#define NN 100000
#define NE 1600000
#define NEO 400000
#define HID 64
#define NL 6
#define BN_EPS 1e-5f

#define SPMM_BLOCKS 6250
#define GRP_ROWS 12500          // NN/8 rows per XCD group
#define CHUNK_NODES 50000       // spmm source-chunk size (6.4MB of hwb)

// hierarchical atomic-free CSR build (R5/R7-proven: device-scope atomics cost
// ~40B HBM write each regardless of XCD locality -> only block-tail atomics)
#define B1CAP 210000            // L1 bucket capacity (mean 200K, sigma~420)
#define BIN_CHUNK 1024
#define BIN_J (BIN_CHUNK / 256)                         // 4
#define BIN_BLOCKS ((NE + BIN_CHUNK - 1) / BIN_CHUNK)   // 1563
#define SB_PER_G 32             // sub-buckets per group
#define SB_ROWS 391             // rows per sub-bucket (ceil(12500/32))
#define SBCAP 7600              // per-sub capacity (mean 6250, sigma~79)
#define BIN2_CHUNK 2048
#define BIN2_BPG 103            // 103*2048 >= B1CAP -> single chunk per block

// ---- d_ws layout (float offsets): ws is 256MiB (harness fill evidence) ----
#define OFF_ECOL 0                        // NE ints
#define OFF_XE   NE                       // NN*64 bf16 = NN*32 f (residual)
#define OFF_AGG  (OFF_XE + NN * 32)       // NN*64 bf16
#define OFF_HWB  (OFF_AGG + NN * 32)      // NN*64 bf16 (contiguous 128B rows)
#define OFF_RP4  (OFF_HWB + NN * 32)      // NN*2+1 ints (chunk-split rowptr)
#define OFF_A32  (OFF_RP4 + 2 * NN + 64)  // NN*64 f32 partial accumulator
// during build: XE region hosts b1 (6.72MB), AGG region hosts b2 (7.78MB);
// both dead before k_embed / first k_spmm write.

// ---- d_out head used as scratch (dead before k_out overwrites) ----
#define OD_DINV   0                      // NN f
#define OD_SS     300960                 // 128 f (scale/shift, final layer)
#define OD_SUMS   301088                 // 2 x 2048 doubles (ping-pong), ends 309280
#define OD_GCUR   309280                 // 8 ints (L1 bucket fills)
#define OD_SCNT   309312                 // 256 ints (sub-bucket fills)
#define OD_SBASE  309568                 // 256 ints (sub-bucket ecol bases)

typedef __attribute__((ext_vector_type(8))) short bf16x8;
typedef __attribute__((ext_vector_type(4))) float f32x4;

static __device__ __forceinline__ unsigned short f2bf(float f) {
    unsigned u = __float_as_uint(f);
    unsigned r = (u + 0x7FFF + ((u >> 16) & 1)) >> 16;  // RNE
    return (unsigned short)r;
}
static __device__ __forceinline__ float bflo(unsigned u) {
    return __uint_as_float(u << 16);
}
static __device__ __forceinline__ float bfhi(unsigned u) {
    return __uint_as_float(u & 0xFFFF0000u);
}

// L1: single read of src/dst; per-wave LDS-aggregated append into 8 group
// buckets, packed (src<<14)|localrow. Global atomics: 8 per block (tails).
__global__ void k_bin(const int* __restrict__ src, const int* __restrict__ dst,
                      int* __restrict__ gcur, int* __restrict__ b1) {
    __shared__ int cw[4][8], bw[4][8], ow[4][8];
    int t = threadIdx.x;
    int w = t >> 6;
    if (t < 32) { ((int*)cw)[t] = 0; ((int*)ow)[t] = 0; }
    __syncthreads();
    int cb = blockIdx.x * BIN_CHUNK;
    int p[BIN_J], g[BIN_J];
#pragma unroll
    for (int j = 0; j < BIN_J; j++) {
        int e = cb + t + j * 256;
        if (e < NE) {
            int s = src[e], d = dst[e];
            g[j] = (unsigned)d / GRP_ROWS;
            p[j] = (s << 14) | (d - g[j] * GRP_ROWS);
            atomicAdd(&cw[w][g[j]], 1);
        } else {
            g[j] = -1;
        }
    }
    __syncthreads();
    if (t < 8) {   // one global atomic per (block, group)
        int c0 = cw[0][t], c1 = cw[1][t], c2 = cw[2][t], c3 = cw[3][t];
        int base = t * B1CAP + atomicAdd(&gcur[t], c0 + c1 + c2 + c3);
        bw[0][t] = base;
        bw[1][t] = base + c0;
        bw[2][t] = base + c0 + c1;
        bw[3][t] = base + c0 + c1 + c2;
    }
    __syncthreads();
#pragma unroll
    for (int j = 0; j < BIN_J; j++) {
        if (g[j] >= 0) {
            int pos = bw[w][g[j]] + atomicAdd(&ow[w][g[j]], 1);
            b1[pos] = p[j];
        }
    }
}

// L2: per group, bin into 32 sub-buckets of 391 rows; repack (src<<9)|subrow.
__global__ void k_bin2(const int* __restrict__ gcur, const int* __restrict__ b1,
                       int* __restrict__ scnt, int* __restrict__ b2) {
    __shared__ int cw[4][SB_PER_G], bw[4][SB_PER_G], ow[4][SB_PER_G];
    int t = threadIdx.x;
    int w = t >> 6;
    if (t < 128) { ((int*)cw)[t] = 0; ((int*)ow)[t] = 0; }
    __syncthreads();
    int g = blockIdx.x & 7;
    int b = blockIdx.x >> 3;
    int n = gcur[g];
    const int* in = b1 + g * B1CAP;
    int c0 = b * BIN2_CHUNK;
    int p[8], sb[8];
#pragma unroll
    for (int j = 0; j < 8; j++) {
        int e = c0 + t + j * 256;
        if (e < n) {
            int v = in[e];
            int lr = v & 16383;
            sb[j] = (unsigned)lr / SB_ROWS;
            p[j] = ((v >> 14) << 9) | (lr - sb[j] * SB_ROWS);
            atomicAdd(&cw[w][sb[j]], 1);
        } else {
            sb[j] = -1;
        }
    }
    __syncthreads();
    if (t < SB_PER_G) {   // one global atomic per (block, sub-bucket)
        int a0 = cw[0][t], a1 = cw[1][t], a2 = cw[2][t], a3 = cw[3][t];
        int base = atomicAdd(&scnt[g * SB_PER_G + t], a0 + a1 + a2 + a3);
        bw[0][t] = base;
        bw[1][t] = base + a0;
        bw[2][t] = base + a0 + a1;
        bw[3][t] = base + a0 + a1 + a2;
    }
    __syncthreads();
#pragma unroll
    for (int j = 0; j < 8; j++) {
        if (sb[j] >= 0) {
            int pos = bw[w][sb[j]] + atomicAdd(&ow[w][sb[j]], 1);
            b2[(g * SB_PER_G + sb[j]) * SBCAP + pos] = p[j];
        }
    }
}

// exclusive scan of 256 sub-bucket sizes -> ecol bases
__global__ void k_scan256(const int* __restrict__ scnt, int* __restrict__ sbase) {
    __shared__ int sh[256];
    int t = threadIdx.x;
    int v = scnt[t];
    sh[t] = v;
    __syncthreads();
    for (int off = 1; off < 256; off <<= 1) {
        int a = (t >= off) ? sh[t - off] : 0;
        __syncthreads();
        sh[t] += a;
        __syncthreads();
    }
    sbase[t] = sh[t] - v;
}

// L3: one block per sub-bucket. Per-(row,chunk) LDS histogram + parallel block
// scan + LDS-cursor scatter. Emits chunk-split rowptr4 + dinv. No global atomics.
__global__ void __launch_bounds__(256) k_build3(
        const int* __restrict__ scnt, const int* __restrict__ sbase,
        const int* __restrict__ b2, int* __restrict__ ecol,
        int* __restrict__ rowptr4, float* __restrict__ dinv) {
    __shared__ int hist[2 * SB_ROWS + 2];
    __shared__ int lofs[2 * SB_ROWS + 2];
    __shared__ int tmp[256];
    __shared__ int lsrc[SBCAP];
    int sb = blockIdx.x;               // 0..255
    int g = sb >> 5, sbl = sb & 31;
    int t = threadIdx.x;
    int n = scnt[sb];
    int base = sbase[sb];
    const int* in = b2 + sb * SBCAP;
    int row0 = g * GRP_ROWS + sbl * SB_ROWS;
    int nrows = GRP_ROWS - sbl * SB_ROWS;
    if (nrows > SB_ROWS) nrows = SB_ROWS;   // last sub of each group: 379 rows
    int tot = 2 * nrows;
    for (int i = t; i < tot; i += 256) hist[i] = 0;
    __syncthreads();
    for (int i = t; i < n; i += 256) {
        int v = in[i];
        lsrc[i] = v;
        int c = ((v >> 9) >= CHUNK_NODES) ? 1 : 0;
        atomicAdd(&hist[(v & 511) * 2 + c], 1);      // LDS atomic
    }
    __syncthreads();
    {   // parallel exclusive scan of hist[0..tot) -> lofs (4 entries/thread)
        int b4 = t * 4;
        int pre[4];
        int s_ = 0;
#pragma unroll
        for (int j = 0; j < 4; j++) {
            int v = (b4 + j < tot) ? hist[b4 + j] : 0;
            pre[j] = s_;
            s_ += v;
        }
        tmp[t] = s_;
        __syncthreads();
        for (int off = 1; off < 256; off <<= 1) {
            int a = (t >= off) ? tmp[t - off] : 0;
            __syncthreads();
            tmp[t] += a;
            __syncthreads();
        }
        int add = (t > 0) ? tmp[t - 1] : 0;
#pragma unroll
        for (int j = 0; j < 4; j++)
            if (b4 + j <= tot) lofs[b4 + j] = add + pre[j];
        __syncthreads();
        if (t == 0) lofs[tot] = n;   // sentinel (overwrites same value)
    }
    __syncthreads();
    for (int r = t; r < nrows; r += 256) {
        rowptr4[(row0 + r) * 2] = base + lofs[r * 2];
        rowptr4[(row0 + r) * 2 + 1] = base + lofs[r * 2 + 1];
        int deg = lofs[r * 2 + 2] - lofs[r * 2];
        dinv[row0 + r] = rsqrtf((float)(deg + 1));   // deg + self-loop
    }
    if (sb == 255 && t == 0) rowptr4[NN * 2] = base + n;   // == NE
    __syncthreads();
    for (int k = t; k < tot; k += 256) hist[k] = lofs[k];  // -> cursors
    __syncthreads();
    for (int i = t; i < n; i += 256) {
        int v = lsrc[i];
        int c = ((v >> 9) >= CHUNK_NODES) ? 1 : 0;
        int pos = atomicAdd(&hist[(v & 511) * 2 + c], 1);  // LDS atomic
        ecol[base + pos] = v >> 9;                          // direct scatter
    }
}

// xe = bf16(x[NN,16] @ W[16,64] + b)
__global__ void k_embed(const float* __restrict__ x, const float* __restrict__ W,
                        const float* __restrict__ b, unsigned short* __restrict__ xe16) {
    __shared__ float Ws[16 * 64];
    __shared__ float bs[64];
    int t = threadIdx.x;
    for (int i = t; i < 16 * 64; i += 256) Ws[i] = W[i];
    if (t < 64) bs[t] = b[t];
    __syncthreads();
    int c = t & 63, r = t >> 6;
    int n0 = blockIdx.x * 64;
    for (int n = n0 + r; n < n0 + 64 && n < NN; n += 4) {
        const float* xr = x + n * 16;
        float acc = bs[c];
#pragma unroll
        for (int k = 0; k < 16; k++) acc = fmaf(xr[k], Ws[k * 64 + c], acc);
        xe16[(size_t)n * 64 + c] = f2bf(acc);
    }
}

// fused: BN-finalize (from sumsPrev) + xe(bf16) += relu(agg(bf16)*sc+sh)
//        + hwb = bf16(dinv*(xe@W))  [MFMA]
__global__ void k_hw(unsigned short* __restrict__ xe16,
                     const float* __restrict__ W, const float* __restrict__ dinv,
                     const unsigned short* __restrict__ agg16,
                     const float* __restrict__ gamma, const float* __restrict__ beta,
                     const double* __restrict__ sumsPrev, double* __restrict__ sumsCur,
                     unsigned short* __restrict__ hwb, int apply) {
    __shared__ unsigned short Wt[64 * 72];   // Wt[c][k], pitch 72
    __shared__ unsigned short Xb[64 * 72];   // Xb[n][k]
    __shared__ float sss[128];
    int t = threadIdx.x;
    int n0 = blockIdx.x * 64;
    if (blockIdx.x == 0) {
        for (int i = t; i < 2048; i += 256) sumsCur[i] = 0.0;
    }
    if (apply && t < 64) {   // in-block BN finalize
        double s = 0.0, q = 0.0;
#pragma unroll
        for (int k = 0; k < 16; k++) {
            s += sumsPrev[k * 128 + t];
            q += sumsPrev[k * 128 + 64 + t];
        }
        double mean = s / (double)NN;
        double var = q / (double)NN - mean * mean;
        float sc = gamma[t] * rsqrtf((float)var + BN_EPS);
        sss[t] = sc;
        sss[64 + t] = beta[t] - (float)mean * sc;
    }

    {   // stage Wt (transpose, bf16)
        int c = t & 63, r = t >> 6;
#pragma unroll
        for (int jj = 0; jj < 4; jj++) {
            float w0 = W[(r * 16 + jj * 4 + 0) * 64 + c];
            float w1 = W[(r * 16 + jj * 4 + 1) * 64 + c];
            float w2 = W[(r * 16 + jj * 4 + 2) * 64 + c];
            float w3 = W[(r * 16 + jj * 4 + 3) * 64 + c];
            uint2 pk;
            pk.x = ((unsigned)f2bf(w1) << 16) | f2bf(w0);
            pk.y = ((unsigned)f2bf(w3) << 16) | f2bf(w2);
            *(uint2*)&Wt[c * 72 + r * 16 + jj * 4] = pk;
        }
    }
    __syncthreads();   // Wt + sss ready

    {   // stage Xb (+apply fusion): thread (n=t>>2, kq=t&3) covers ch kq*16..+15
        int n = t >> 2, kq = t & 3;
        int node = n0 + n;
        unsigned xs[8] = {0, 0, 0, 0, 0, 0, 0, 0};
        if (node < NN) {
            const uint4* xr = (const uint4*)(xe16 + (size_t)node * 64 + kq * 16);
            uint4 x0 = xr[0], x1 = xr[1];
            xs[0] = x0.x; xs[1] = x0.y; xs[2] = x0.z; xs[3] = x0.w;
            xs[4] = x1.x; xs[5] = x1.y; xs[6] = x1.z; xs[7] = x1.w;
            if (apply) {
                const uint4* ar = (const uint4*)(agg16 + (size_t)node * 64 + kq * 16);
                uint4 a0 = ar[0], a1 = ar[1];
                unsigned as[8] = {a0.x, a0.y, a0.z, a0.w, a1.x, a1.y, a1.z, a1.w};
                int c = kq * 16;
#pragma unroll
                for (int i = 0; i < 8; i++) {
                    float v0 = bflo(xs[i]) +
                               fmaxf(fmaf(bflo(as[i]), sss[c + 2 * i], sss[64 + c + 2 * i]), 0.f);
                    float v1 = bfhi(xs[i]) +
                               fmaxf(fmaf(bfhi(as[i]), sss[c + 2 * i + 1], sss[64 + c + 2 * i + 1]), 0.f);
                    xs[i] = ((unsigned)f2bf(v1) << 16) | f2bf(v0);
                }
                uint4* xw = (uint4*)(xe16 + (size_t)node * 64 + kq * 16);
                xw[0] = make_uint4(xs[0], xs[1], xs[2], xs[3]);
                xw[1] = make_uint4(xs[4], xs[5], xs[6], xs[7]);
            }
        }
        *(uint4*)&Xb[n * 72 + kq * 16] = make_uint4(xs[0], xs[1], xs[2], xs[3]);
        *(uint4*)&Xb[n * 72 + kq * 16 + 8] = make_uint4(xs[4], xs[5], xs[6], xs[7]);
    }
    __syncthreads();

    int lane = t & 63, w = t >> 6;
    int m = lane & 15, quad = lane >> 4;
    f32x4 acc[4];
#pragma unroll
    for (int tc = 0; tc < 4; tc++) acc[tc] = (f32x4){0.f, 0.f, 0.f, 0.f};
#pragma unroll
    for (int s = 0; s < 2; s++) {
        bf16x8 bfr = *(const bf16x8*)&Xb[(w * 16 + m) * 72 + s * 32 + quad * 8];
#pragma unroll
        for (int tc = 0; tc < 4; tc++) {
            bf16x8 afr = *(const bf16x8*)&Wt[(tc * 16 + m) * 72 + s * 32 + quad * 8];
            acc[tc] = __builtin_amdgcn_mfma_f32_16x16x32_bf16(afr, bfr, acc[tc], 0, 0, 0);
        }
    }
    int node = n0 + w * 16 + m;
    if (node < NN) {
        float di = dinv[node];
#pragma unroll
        for (int tc = 0; tc < 4; tc++) {
            int c0 = tc * 16 + quad * 4;
            uint2 pk;
            pk.x = ((unsigned)f2bf(acc[tc][1] * di) << 16) | f2bf(acc[tc][0] * di);
            pk.y = ((unsigned)f2bf(acc[tc][3] * di) << 16) | f2bf(acc[tc][2] * di);
            *(uint2*)(hwb + (size_t)node * 64 + c0) = pk;
        }
    }
}

// spmm pass A (chunk 0, sources < 50000): self-row + chunk-0 gathers -> f32
// partials in agg32 (nt stream). All concurrent gathers hit a 6.4MB window.
__global__ void k_spmmA(const int* __restrict__ rowptr4, const int* __restrict__ ecol,
                        const unsigned short* __restrict__ hwb,
                        float* __restrict__ agg32) {
    int t = threadIdx.x;
    int w = t >> 6, l = t & 63;
    int r = l >> 4;          // row slot 0..3
    int sub = (l >> 3) & 1;  // edge sub-group
    int q = l & 7;           // channel quad
    const uint4* hw4 = (const uint4*)hwb;
    for (int row0 = blockIdx.x * 16 + w * 4; row0 < NN; row0 += SPMM_BLOCKS * 16) {
        int row = row0 + r;
        bool valid = row < NN;
        int p0 = 0, p1 = 0;
        float a[8];
#pragma unroll
        for (int j = 0; j < 8; j++) a[j] = 0.f;
        if (valid) {
            p0 = rowptr4[row * 2];
            p1 = rowptr4[row * 2 + 1];
            if (sub == 0) {   // self-loop term
                uint4 sv = hw4[(size_t)row * 8 + q];
                a[0] = bflo(sv.x); a[1] = bfhi(sv.x); a[2] = bflo(sv.y); a[3] = bfhi(sv.y);
                a[4] = bflo(sv.z); a[5] = bfhi(sv.z); a[6] = bflo(sv.w); a[7] = bfhi(sv.w);
            }
        }
        int p = p0 + sub;
        for (; p + 2 < p1; p += 4) {
            int s0 = ecol[p], s1 = ecol[p + 2];
            uint4 u0 = hw4[(size_t)s0 * 8 + q];
            uint4 u1 = hw4[(size_t)s1 * 8 + q];
            a[0] += bflo(u0.x); a[1] += bfhi(u0.x); a[2] += bflo(u0.y); a[3] += bfhi(u0.y);
            a[4] += bflo(u0.z); a[5] += bfhi(u0.z); a[6] += bflo(u0.w); a[7] += bfhi(u0.w);
            a[0] += bflo(u1.x); a[1] += bfhi(u1.x); a[2] += bflo(u1.y); a[3] += bfhi(u1.y);
            a[4] += bflo(u1.z); a[5] += bfhi(u1.z); a[6] += bflo(u1.w); a[7] += bfhi(u1.w);
        }
        if (p < p1) {
            int s0 = ecol[p];
            uint4 u0 = hw4[(size_t)s0 * 8 + q];
            a[0] += bflo(u0.x); a[1] += bfhi(u0.x); a[2] += bflo(u0.y); a[3] += bfhi(u0.y);
            a[4] += bflo(u0.z); a[5] += bfhi(u0.z); a[6] += bflo(u0.w); a[7] += bfhi(u0.w);
        }
#pragma unroll
        for (int j = 0; j < 8; j++) a[j] += __shfl_xor(a[j], 8, 64);
        if (valid && sub == 0) {
            f32x4 v0 = {a[0], a[1], a[2], a[3]};
            f32x4 v1 = {a[4], a[5], a[6], a[7]};
            float* dst = agg32 + (size_t)row * 64 + q * 8;
            __builtin_nontemporal_store(v0, (f32x4*)dst);
            __builtin_nontemporal_store(v1, (f32x4*)(dst + 4));
        }
    }
}

// spmm pass B (chunk 1): gathers from upper 6.4MB window, adds agg32 partials,
// finalizes: *dinv, bf16 round, agg16 store, BN stats on rounded values.
__global__ void k_spmmB(const int* __restrict__ rowptr4, const int* __restrict__ ecol,
                        const unsigned short* __restrict__ hwb, const float* __restrict__ dinv,
                        const float* __restrict__ agg32,
                        unsigned short* __restrict__ agg16, double* __restrict__ sums) {
    int t = threadIdx.x;
    int w = t >> 6, l = t & 63;
    int r = l >> 4;
    int sub = (l >> 3) & 1;
    int q = l & 7;
    const uint4* hw4 = (const uint4*)hwb;
    float ls[8], lq[8];
#pragma unroll
    for (int j = 0; j < 8; j++) { ls[j] = 0.f; lq[j] = 0.f; }
    for (int row0 = blockIdx.x * 16 + w * 4; row0 < NN; row0 += SPMM_BLOCKS * 16) {
        int row = row0 + r;
        bool valid = row < NN;
        int p0 = 0, p1 = 0;
        float a[8];
#pragma unroll
        for (int j = 0; j < 8; j++) a[j] = 0.f;
        if (valid) {
            p0 = rowptr4[row * 2 + 1];
            p1 = rowptr4[row * 2 + 2];
        }
        int p = p0 + sub;
        for (; p + 2 < p1; p += 4) {
            int s0 = ecol[p], s1 = ecol[p + 2];
            uint4 u0 = hw4[(size_t)s0 * 8 + q];
            uint4 u1 = hw4[(size_t)s1 * 8 + q];
            a[0] += bflo(u0.x); a[1] += bfhi(u0.x); a[2] += bflo(u0.y); a[3] += bfhi(u0.y);
            a[4] += bflo(u0.z); a[5] += bfhi(u0.z); a[6] += bflo(u0.w); a[7] += bfhi(u0.w);
            a[0] += bflo(u1.x); a[1] += bfhi(u1.x); a[2] += bflo(u1.y); a[3] += bfhi(u1.y);
            a[4] += bflo(u1.z); a[5] += bfhi(u1.z); a[6] += bflo(u1.w); a[7] += bfhi(u1.w);
        }
        if (p < p1) {
            int s0 = ecol[p];
            uint4 u0 = hw4[(size_t)s0 * 8 + q];
            a[0] += bflo(u0.x); a[1] += bfhi(u0.x); a[2] += bflo(u0.y); a[3] += bfhi(u0.y);
            a[4] += bflo(u0.z); a[5] += bfhi(u0.z); a[6] += bflo(u0.w); a[7] += bfhi(u0.w);
        }
#pragma unroll
        for (int j = 0; j < 8; j++) a[j] += __shfl_xor(a[j], 8, 64);
        if (valid && sub == 0) {
            const float* srcp = agg32 + (size_t)row * 64 + q * 8;
            f32x4 b0 = __builtin_nontemporal_load((const f32x4*)srcp);
            f32x4 b1 = __builtin_nontemporal_load((const f32x4*)(srcp + 4));
            a[0] += b0[0]; a[1] += b0[1]; a[2] += b0[2]; a[3] += b0[3];
            a[4] += b1[0]; a[5] += b1[1]; a[6] += b1[2]; a[7] += b1[3];
            float di = dinv[row];
            unsigned pk[4];
#pragma unroll
            for (int j = 0; j < 4; j++) {
                float v0 = a[2 * j] * di, v1 = a[2 * j + 1] * di;
                pk[j] = ((unsigned)f2bf(v1) << 16) | f2bf(v0);
            }
            *(uint4*)(agg16 + (size_t)row * 64 + 8 * q) = make_uint4(pk[0], pk[1], pk[2], pk[3]);
            // stats on the rounded (stored) values -> BN self-consistent
#pragma unroll
            for (int j = 0; j < 4; j++) {
                float v0 = bflo(pk[j]), v1 = bfhi(pk[j]);
                ls[2 * j] += v0; ls[2 * j + 1] += v1;
                lq[2 * j] = fmaf(v0, v0, lq[2 * j]);
                lq[2 * j + 1] = fmaf(v1, v1, lq[2 * j + 1]);
            }
        }
    }
#pragma unroll
    for (int j = 0; j < 8; j++) {
        ls[j] += __shfl_xor(ls[j], 16, 64); ls[j] += __shfl_xor(ls[j], 32, 64);
        lq[j] += __shfl_xor(lq[j], 16, 64); lq[j] += __shfl_xor(lq[j], 32, 64);
    }
    __shared__ float Ss[4][64], Sq[4][64];
    if (l < 8) {
#pragma unroll
        for (int j = 0; j < 8; j++) {
            Ss[w][8 * l + j] = ls[j];
            Sq[w][8 * l + j] = lq[j];
        }
    }
    __syncthreads();
    if (t < 64) {
        float a = Ss[0][t] + Ss[1][t] + Ss[2][t] + Ss[3][t];
        float b = Sq[0][t] + Sq[1][t] + Sq[2][t] + Sq[3][t];
        double* sh = sums + (blockIdx.x & 15) * 128;
        atomicAdd(&sh[t], (double)a);
        atomicAdd(&sh[64 + t], (double)b);
    }
}

// final-layer BN finalize (single launch after loop)
__global__ void k_finalize(const double* __restrict__ sums, const float* __restrict__ gamma,
                           const float* __restrict__ beta, float* __restrict__ ss) {
    int c = threadIdx.x;  // 64 threads
    double s = 0.0, q = 0.0;
#pragma unroll
    for (int k = 0; k < 16; k++) { s += sums[k * 128 + c]; q += sums[k * 128 + 64 + c]; }
    double mean = s / (double)NN;
    double var = q / (double)NN - mean * mean;
    float sc = gamma[c] * rsqrtf((float)var + BN_EPS);
    ss[c] = sc;
    ss[64 + c] = beta[c] - (float)mean * sc;
}

// final layer: xe16 += relu(agg16*scale + shift)  (in-place bf16 update)
__global__ void k_apply(const unsigned short* __restrict__ agg16, const float* __restrict__ ss,
                        unsigned short* __restrict__ xe16) {
    int i = blockIdx.x * blockDim.x + threadIdx.x;   // uint4 index, NN*8 total
    if (i < NN * 8) {
        int c0 = (i & 7) * 8;
        uint4 av = *(const uint4*)(agg16 + (size_t)i * 8);
        uint4 xv = *(const uint4*)(xe16 + (size_t)i * 8);
        unsigned as[4] = {av.x, av.y, av.z, av.w};
        unsigned xs[4] = {xv.x, xv.y, xv.z, xv.w};
#pragma unroll
        for (int j = 0; j < 4; j++) {
            int c = c0 + 2 * j;
            float v0 = bflo(xs[j]) + fmaxf(fmaf(bflo(as[j]), ss[c], ss[64 + c]), 0.f);
            float v1 = bfhi(xs[j]) + fmaxf(fmaf(bfhi(as[j]), ss[c + 1], ss[64 + c + 1]), 0.f);
            xs[j] = ((unsigned)f2bf(v1) << 16) | f2bf(v0);
        }
        *(uint4*)(xe16 + (size_t)i * 8) = make_uint4(xs[0], xs[1], xs[2], xs[3]);
    }
}

// out[e] = [xe16[s]; xe16[d]] @ fc_W + fc_b   (bf16 rows: 128B/row gather)
__global__ void k_out(const int* __restrict__ esrc, const int* __restrict__ edst,
                      const unsigned short* __restrict__ xe16, const float* __restrict__ fcW,
                      const float* __restrict__ fcb, float* __restrict__ out) {
    __shared__ float Ws[256];
    __shared__ float bs[2];
    int t = threadIdx.x;
    for (int i = t; i < 256; i += 256) Ws[i] = fcW[i];
    if (t < 2) bs[t] = fcb[t];
    __syncthreads();
    int e = blockIdx.x * blockDim.x + t;
    if (e < NEO) {
        int s = esrc[e], d = edst[e];
        const uint4* rs = (const uint4*)(xe16 + (size_t)s * 64);
        const uint4* rd = (const uint4*)(xe16 + (size_t)d * 64);
        float a0 = bs[0], a1 = bs[1];
#pragma unroll
        for (int i = 0; i < 8; i++) {
            uint4 v = rs[i];
            int c = i * 8;
            a0 += bflo(v.x) * Ws[(c + 0) * 2] + bfhi(v.x) * Ws[(c + 1) * 2] +
                  bflo(v.y) * Ws[(c + 2) * 2] + bfhi(v.y) * Ws[(c + 3) * 2] +
                  bflo(v.z) * Ws[(c + 4) * 2] + bfhi(v.z) * Ws[(c + 5) * 2] +
                  bflo(v.w) * Ws[(c + 6) * 2] + bfhi(v.w) * Ws[(c + 7) * 2];
            a1 += bflo(v.x) * Ws[(c + 0) * 2 + 1] + bfhi(v.x) * Ws[(c + 1) * 2 + 1] +
                  bflo(v.y) * Ws[(c + 2) * 2 + 1] + bfhi(v.y) * Ws[(c + 3) * 2 + 1] +
                  bflo(v.z) * Ws[(c + 4) * 2 + 1] + bfhi(v.z) * Ws[(c + 5) * 2 + 1] +
                  bflo(v.w) * Ws[(c + 6) * 2 + 1] + bfhi(v.w) * Ws[(c + 7) * 2 + 1];
        }
#pragma unroll
        for (int i = 0; i < 8; i++) {
            uint4 v = rd[i];
            int c = 64 + i * 8;
            a0 += bflo(v.x) * Ws[(c + 0) * 2] + bfhi(v.x) * Ws[(c + 1) * 2] +
                  bflo(v.y) * Ws[(c + 2) * 2] + bfhi(v.y) * Ws[(c + 3) * 2] +
                  bflo(v.z) * Ws[(c + 4) * 2] + bfhi(v.z) * Ws[(c + 5) * 2] +
                  bflo(v.w) * Ws[(c + 6) * 2] + bfhi(v.w) * Ws[(c + 7) * 2];
            a1 += bflo(v.x) * Ws[(c + 0) * 2 + 1] + bfhi(v.x) * Ws[(c + 1) * 2 + 1] +
                  bflo(v.y) * Ws[(c + 2) * 2 + 1] + bfhi(v.y) * Ws[(c + 3) * 2 + 1] +
                  bflo(v.z) * Ws[(c + 4) * 2 + 1] + bfhi(v.z) * Ws[(c + 5) * 2 + 1] +
                  bflo(v.w) * Ws[(c + 6) * 2 + 1] + bfhi(v.w) * Ws[(c + 7) * 2 + 1];
        }
        out[e * 2] = a0;
        out[e * 2 + 1] = a1;
    }
}

extern "C" void kernel_launch(void* const* d_in, const int* in_sizes, int n_in,
                              void* d_out, int out_size, void* d_ws, size_t ws_size,
                              hipStream_t stream) {
    const float* x      = (const float*)d_in[0];
    const int*   ei     = (const int*)d_in[1];
    const int*   eio    = (const int*)d_in[2];
    const float* W_emb  = (const float*)d_in[3];
    const float* b_emb  = (const float*)d_in[4];
    const float* conv_W = (const float*)d_in[5];
    // d_in[6] conv_b: cancels inside BN
    const float* bn_g   = (const float*)d_in[7];
    const float* bn_b   = (const float*)d_in[8];
    const float* fc_W   = (const float*)d_in[9];
    const float* fc_b   = (const float*)d_in[10];
    float* out = (float*)d_out;

    float* ws   = (float*)d_ws;
    int*   ecol = (int*)(ws + OFF_ECOL);
    unsigned short* xe16  = (unsigned short*)(ws + OFF_XE);
    unsigned short* agg16 = (unsigned short*)(ws + OFF_AGG);
    unsigned short* hwb   = (unsigned short*)(ws + OFF_HWB);
    int*   rowptr4 = (int*)(ws + OFF_RP4);
    float* agg32   = ws + OFF_A32;
    // bucket scratch: XE/AGG regions are dead until k_embed / first spmm
    int* b1 = (int*)(ws + OFF_XE);
    int* b2 = (int*)(ws + OFF_AGG);

    float* od     = (float*)d_out;
    float* dinv   = od + OD_DINV;
    float* ss     = od + OD_SS;
    double* sums  = (double*)(od + OD_SUMS);   // 2 x 2048 doubles, ping-pong
    int*   gcur   = (int*)(od + OD_GCUR);
    int*   scnt   = (int*)(od + OD_SCNT);
    int*   sbase  = (int*)(od + OD_SBASE);

    const int* src  = ei;
    const int* dst  = ei + NE;
    const int* esrc = eio;
    const int* edst = eio + NEO;

    // ---- atomic-free hierarchical CSR build (chunk-split ecol) ----
    (void)hipMemsetAsync(gcur, 0, 8 * sizeof(int), stream);
    (void)hipMemsetAsync(scnt, 0, 256 * sizeof(int), stream);
    k_bin<<<BIN_BLOCKS, 256, 0, stream>>>(src, dst, gcur, b1);
    k_bin2<<<8 * BIN2_BPG, 256, 0, stream>>>(gcur, b1, scnt, b2);
    k_scan256<<<1, 256, 0, stream>>>(scnt, sbase);
    k_build3<<<256, 256, 0, stream>>>(scnt, sbase, b2, ecol, rowptr4, dinv);

    k_embed<<<(NN + 63) / 64, 256, 0, stream>>>(x, W_emb, b_emb, xe16);

    for (int l = 0; l < NL; l++) {
        double* sumsPrev = sums + ((l + 1) & 1) * 2048;
        double* sumsCur  = sums + (l & 1) * 2048;
        k_hw<<<(NN + 63) / 64, 256, 0, stream>>>(xe16, conv_W + l * 64 * 64, dinv, agg16,
                                                 bn_g + (l ? (l - 1) * 64 : 0),
                                                 bn_b + (l ? (l - 1) * 64 : 0),
                                                 sumsPrev, sumsCur, hwb, l > 0 ? 1 : 0);
        k_spmmA<<<SPMM_BLOCKS, 256, 0, stream>>>(rowptr4, ecol, hwb, agg32);
        k_spmmB<<<SPMM_BLOCKS, 256, 0, stream>>>(rowptr4, ecol, hwb, dinv, agg32,
                                                 agg16, sumsCur);
    }
    k_finalize<<<1, 64, 0, stream>>>(sums + ((NL - 1) & 1) * 2048,
                                     bn_g + (NL - 1) * 64, bn_b + (NL - 1) * 64, ss);
    k_apply<<<(NN * 8 + 255) / 256, 256, 0, stream>>>(agg16, ss, xe16);

    k_out<<<(NEO + 255) / 256, 256, 0, stream>>>(esrc, edst, xe16, fc_W, fc_b, out);
}

// Round 9
// 482.628 us; speedup vs baseline: 1.1478x; 1.1478x over previous
//
#include <hip/hip_runtime.h>

#define NN 100000
#define NE 1600000
#define NEO 400000
#define HID 64
#define NL 6
#define BN_EPS 1e-5f

#define SPMM_BLOCKS 6250
#define GRP_ROWS 12500          // NN/8 rows per XCD group

// hierarchical atomic-free CSR build (R7-proven: device-scope atomics cost
// ~40B HBM write each regardless of XCD locality -> only block-tail atomics)
#define B1CAP 210000            // L1 bucket capacity (mean 200K, sigma~420)
#define BIN_CHUNK 1024
#define BIN_J (BIN_CHUNK / 256)                         // 4
#define BIN_BLOCKS ((NE + BIN_CHUNK - 1) / BIN_CHUNK)   // 1563
#define SB_PER_G 32             // sub-buckets per group
#define SB_ROWS 391             // rows per sub-bucket (ceil(12500/32))
#define SBCAP 7600              // per-sub capacity (mean 6250, sigma~79)
#define BIN2_CHUNK 2048
#define BIN2_BPG 103            // 103*2048 >= B1CAP -> single chunk per block

// ---- d_ws layout (float offsets) ----
#define OFF_ECOL 0                        // NE ints
#define OFF_XE   NE                       // NN*64 bf16 = NN*32 f (residual)
#define OFF_AGG  (OFF_XE + NN * 32)       // NN*64 bf16
#define OFF_HWB  (OFF_AGG + NN * 32)      // NN*64 bf16 (contiguous 128B rows)
// during build: XE region hosts b1 (6.72MB), AGG region hosts b2 (7.78MB);
// both dead before k_embed / first k_spmm write.

// ---- d_out head used as scratch (dead before k_out overwrites) ----
#define OD_DINV   0                      // NN f
#define OD_ROWPTR 100352                 // NN+1 ints
#define OD_SS     300960                 // 128 f (scale/shift, final layer)
#define OD_SUMS   301088                 // 2 x 2048 doubles (ping-pong), ends 309280
#define OD_GCUR   309280                 // 8 ints (L1 bucket fills)
#define OD_SCNT   309312                 // 256 ints (sub-bucket fills)
#define OD_SBASE  309568                 // 256 ints (sub-bucket ecol bases)

typedef __attribute__((ext_vector_type(8))) short bf16x8;
typedef __attribute__((ext_vector_type(4))) float f32x4;

static __device__ __forceinline__ unsigned short f2bf(float f) {
    unsigned u = __float_as_uint(f);
    unsigned r = (u + 0x7FFF + ((u >> 16) & 1)) >> 16;  // RNE
    return (unsigned short)r;
}
static __device__ __forceinline__ float bflo(unsigned u) {
    return __uint_as_float(u << 16);
}
static __device__ __forceinline__ float bfhi(unsigned u) {
    return __uint_as_float(u & 0xFFFF0000u);
}

// L1: single read of src/dst; per-wave LDS-aggregated append into 8 group
// buckets, packed (src<<14)|localrow. Global atomics: 8 per block (tails).
__global__ void k_bin(const int* __restrict__ src, const int* __restrict__ dst,
                      int* __restrict__ gcur, int* __restrict__ b1) {
    __shared__ int cw[4][8], bw[4][8], ow[4][8];
    int t = threadIdx.x;
    int w = t >> 6;
    if (t < 32) { ((int*)cw)[t] = 0; ((int*)ow)[t] = 0; }
    __syncthreads();
    int cb = blockIdx.x * BIN_CHUNK;
    int p[BIN_J], g[BIN_J];
#pragma unroll
    for (int j = 0; j < BIN_J; j++) {
        int e = cb + t + j * 256;
        if (e < NE) {
            int s = src[e], d = dst[e];
            g[j] = (unsigned)d / GRP_ROWS;
            p[j] = (s << 14) | (d - g[j] * GRP_ROWS);
            atomicAdd(&cw[w][g[j]], 1);
        } else {
            g[j] = -1;
        }
    }
    __syncthreads();
    if (t < 8) {   // one global atomic per (block, group)
        int c0 = cw[0][t], c1 = cw[1][t], c2 = cw[2][t], c3 = cw[3][t];
        int base = t * B1CAP + atomicAdd(&gcur[t], c0 + c1 + c2 + c3);
        bw[0][t] = base;
        bw[1][t] = base + c0;
        bw[2][t] = base + c0 + c1;
        bw[3][t] = base + c0 + c1 + c2;
    }
    __syncthreads();
#pragma unroll
    for (int j = 0; j < BIN_J; j++) {
        if (g[j] >= 0) {
            int pos = bw[w][g[j]] + atomicAdd(&ow[w][g[j]], 1);
            b1[pos] = p[j];
        }
    }
}

// L2: per group, bin into 32 sub-buckets of 391 rows; repack (src<<9)|subrow.
__global__ void k_bin2(const int* __restrict__ gcur, const int* __restrict__ b1,
                       int* __restrict__ scnt, int* __restrict__ b2) {
    __shared__ int cw[4][SB_PER_G], bw[4][SB_PER_G], ow[4][SB_PER_G];
    int t = threadIdx.x;
    int w = t >> 6;
    if (t < 128) { ((int*)cw)[t] = 0; ((int*)ow)[t] = 0; }
    __syncthreads();
    int g = blockIdx.x & 7;
    int b = blockIdx.x >> 3;
    int n = gcur[g];
    const int* in = b1 + g * B1CAP;
    int c0 = b * BIN2_CHUNK;
    int p[8], sb[8];
#pragma unroll
    for (int j = 0; j < 8; j++) {
        int e = c0 + t + j * 256;
        if (e < n) {
            int v = in[e];
            int lr = v & 16383;
            sb[j] = (unsigned)lr / SB_ROWS;
            p[j] = ((v >> 14) << 9) | (lr - sb[j] * SB_ROWS);
            atomicAdd(&cw[w][sb[j]], 1);
        } else {
            sb[j] = -1;
        }
    }
    __syncthreads();
    if (t < SB_PER_G) {   // one global atomic per (block, sub-bucket)
        int a0 = cw[0][t], a1 = cw[1][t], a2 = cw[2][t], a3 = cw[3][t];
        int base = atomicAdd(&scnt[g * SB_PER_G + t], a0 + a1 + a2 + a3);
        bw[0][t] = base;
        bw[1][t] = base + a0;
        bw[2][t] = base + a0 + a1;
        bw[3][t] = base + a0 + a1 + a2;
    }
    __syncthreads();
#pragma unroll
    for (int j = 0; j < 8; j++) {
        if (sb[j] >= 0) {
            int pos = bw[w][sb[j]] + atomicAdd(&ow[w][sb[j]], 1);
            b2[(g * SB_PER_G + sb[j]) * SBCAP + pos] = p[j];
        }
    }
}

// exclusive scan of 256 sub-bucket sizes -> ecol bases
__global__ void k_scan256(const int* __restrict__ scnt, int* __restrict__ sbase) {
    __shared__ int sh[256];
    int t = threadIdx.x;
    int v = scnt[t];
    sh[t] = v;
    __syncthreads();
    for (int off = 1; off < 256; off <<= 1) {
        int a = (t >= off) ? sh[t - off] : 0;
        __syncthreads();
        sh[t] += a;
        __syncthreads();
    }
    sbase[t] = sh[t] - v;
}

// L3: one block per sub-bucket. LDS histogram + scan + scatter -> sequential
// full-line ecol writes; rowptr/dinv emitted directly. ZERO global atomics.
__global__ void __launch_bounds__(256) k_build3(
        const int* __restrict__ scnt, const int* __restrict__ sbase,
        const int* __restrict__ b2, int* __restrict__ ecol,
        int* __restrict__ rowptr, float* __restrict__ dinv) {
    __shared__ int hist[SB_ROWS + 1];
    __shared__ int lofs[SB_ROWS + 1];
    __shared__ int lsrc[SBCAP];
    __shared__ int lout[SBCAP];
    int sb = blockIdx.x;               // 0..255
    int g = sb >> 5, sbl = sb & 31;
    int t = threadIdx.x;
    int n = scnt[sb];
    int base = sbase[sb];
    const int* in = b2 + sb * SBCAP;
    int row0 = g * GRP_ROWS + sbl * SB_ROWS;
    int nrows = GRP_ROWS - sbl * SB_ROWS;
    if (nrows > SB_ROWS) nrows = SB_ROWS;   // last sub of each group: 379 rows
    for (int i = t; i < nrows; i += 256) hist[i] = 0;
    __syncthreads();
    for (int i = t; i < n; i += 256) {
        int v = in[i];
        lsrc[i] = v;
        atomicAdd(&hist[v & 511], 1);      // LDS atomic
    }
    __syncthreads();
    if (t == 0) {                          // serial scan, <=391 elements
        int acc = 0;
        for (int r = 0; r < nrows; r++) { lofs[r] = acc; acc += hist[r]; }
        lofs[nrows] = acc;
    }
    __syncthreads();
    for (int r = t; r < nrows; r += 256) {
        rowptr[row0 + r] = base + lofs[r];
        dinv[row0 + r] = rsqrtf((float)(hist[r] + 1));   // deg + self-loop
    }
    if (sb == 255 && t == 0) rowptr[NN] = base + n;      // == NE
    __syncthreads();
    for (int r = t; r < nrows; r += 256) hist[r] = lofs[r];  // -> cursors
    __syncthreads();
    for (int i = t; i < n; i += 256) {
        int v = lsrc[i];
        int pos = atomicAdd(&hist[v & 511], 1);          // LDS atomic
        lout[pos] = v >> 9;
    }
    __syncthreads();
    for (int i = t; i < n; i += 256) ecol[base + i] = lout[i];
}

// xe = bf16(x[NN,16] @ W[16,64] + b)
__global__ void k_embed(const float* __restrict__ x, const float* __restrict__ W,
                        const float* __restrict__ b, unsigned short* __restrict__ xe16) {
    __shared__ float Ws[16 * 64];
    __shared__ float bs[64];
    int t = threadIdx.x;
    for (int i = t; i < 16 * 64; i += 256) Ws[i] = W[i];
    if (t < 64) bs[t] = b[t];
    __syncthreads();
    int c = t & 63, r = t >> 6;
    int n0 = blockIdx.x * 64;
    for (int n = n0 + r; n < n0 + 64 && n < NN; n += 4) {
        const float* xr = x + n * 16;
        float acc = bs[c];
#pragma unroll
        for (int k = 0; k < 16; k++) acc = fmaf(xr[k], Ws[k * 64 + c], acc);
        xe16[(size_t)n * 64 + c] = f2bf(acc);
    }
}

// fused: BN-finalize (from sumsPrev) + xe(bf16) += relu(agg(bf16)*sc+sh)
//        + hwb = bf16(dinv*(xe@W))  [MFMA]
__global__ void k_hw(unsigned short* __restrict__ xe16,
                     const float* __restrict__ W, const float* __restrict__ dinv,
                     const unsigned short* __restrict__ agg16,
                     const float* __restrict__ gamma, const float* __restrict__ beta,
                     const double* __restrict__ sumsPrev, double* __restrict__ sumsCur,
                     unsigned short* __restrict__ hwb, int apply) {
    __shared__ unsigned short Wt[64 * 72];   // Wt[c][k], pitch 72
    __shared__ unsigned short Xb[64 * 72];   // Xb[n][k]
    __shared__ float sss[128];
    int t = threadIdx.x;
    int n0 = blockIdx.x * 64;
    if (blockIdx.x == 0) {
        for (int i = t; i < 2048; i += 256) sumsCur[i] = 0.0;
    }
    if (apply && t < 64) {   // in-block BN finalize
        double s = 0.0, q = 0.0;
#pragma unroll
        for (int k = 0; k < 16; k++) {
            s += sumsPrev[k * 128 + t];
            q += sumsPrev[k * 128 + 64 + t];
        }
        double mean = s / (double)NN;
        double var = q / (double)NN - mean * mean;
        float sc = gamma[t] * rsqrtf((float)var + BN_EPS);
        sss[t] = sc;
        sss[64 + t] = beta[t] - (float)mean * sc;
    }

    {   // stage Wt (transpose, bf16)
        int c = t & 63, r = t >> 6;
#pragma unroll
        for (int jj = 0; jj < 4; jj++) {
            float w0 = W[(r * 16 + jj * 4 + 0) * 64 + c];
            float w1 = W[(r * 16 + jj * 4 + 1) * 64 + c];
            float w2 = W[(r * 16 + jj * 4 + 2) * 64 + c];
            float w3 = W[(r * 16 + jj * 4 + 3) * 64 + c];
            uint2 pk;
            pk.x = ((unsigned)f2bf(w1) << 16) | f2bf(w0);
            pk.y = ((unsigned)f2bf(w3) << 16) | f2bf(w2);
            *(uint2*)&Wt[c * 72 + r * 16 + jj * 4] = pk;
        }
    }
    __syncthreads();   // Wt + sss ready

    {   // stage Xb (+apply fusion): thread (n=t>>2, kq=t&3) covers ch kq*16..+15
        int n = t >> 2, kq = t & 3;
        int node = n0 + n;
        unsigned xs[8] = {0, 0, 0, 0, 0, 0, 0, 0};
        if (node < NN) {
            const uint4* xr = (const uint4*)(xe16 + (size_t)node * 64 + kq * 16);
            uint4 x0 = xr[0], x1 = xr[1];
            xs[0] = x0.x; xs[1] = x0.y; xs[2] = x0.z; xs[3] = x0.w;
            xs[4] = x1.x; xs[5] = x1.y; xs[6] = x1.z; xs[7] = x1.w;
            if (apply) {
                const uint4* ar = (const uint4*)(agg16 + (size_t)node * 64 + kq * 16);
                uint4 a0 = ar[0], a1 = ar[1];
                unsigned as[8] = {a0.x, a0.y, a0.z, a0.w, a1.x, a1.y, a1.z, a1.w};
                int c = kq * 16;
#pragma unroll
                for (int i = 0; i < 8; i++) {
                    float v0 = bflo(xs[i]) +
                               fmaxf(fmaf(bflo(as[i]), sss[c + 2 * i], sss[64 + c + 2 * i]), 0.f);
                    float v1 = bfhi(xs[i]) +
                               fmaxf(fmaf(bfhi(as[i]), sss[c + 2 * i + 1], sss[64 + c + 2 * i + 1]), 0.f);
                    xs[i] = ((unsigned)f2bf(v1) << 16) | f2bf(v0);
                }
                uint4* xw = (uint4*)(xe16 + (size_t)node * 64 + kq * 16);
                xw[0] = make_uint4(xs[0], xs[1], xs[2], xs[3]);
                xw[1] = make_uint4(xs[4], xs[5], xs[6], xs[7]);
            }
        }
        *(uint4*)&Xb[n * 72 + kq * 16] = make_uint4(xs[0], xs[1], xs[2], xs[3]);
        *(uint4*)&Xb[n * 72 + kq * 16 + 8] = make_uint4(xs[4], xs[5], xs[6], xs[7]);
    }
    __syncthreads();

    int lane = t & 63, w = t >> 6;
    int m = lane & 15, quad = lane >> 4;
    f32x4 acc[4];
#pragma unroll
    for (int tc = 0; tc < 4; tc++) acc[tc] = (f32x4){0.f, 0.f, 0.f, 0.f};
#pragma unroll
    for (int s = 0; s < 2; s++) {
        bf16x8 bfr = *(const bf16x8*)&Xb[(w * 16 + m) * 72 + s * 32 + quad * 8];
#pragma unroll
        for (int tc = 0; tc < 4; tc++) {
            bf16x8 afr = *(const bf16x8*)&Wt[(tc * 16 + m) * 72 + s * 32 + quad * 8];
            acc[tc] = __builtin_amdgcn_mfma_f32_16x16x32_bf16(afr, bfr, acc[tc], 0, 0, 0);
        }
    }
    int node = n0 + w * 16 + m;
    if (node < NN) {
        float di = dinv[node];
#pragma unroll
        for (int tc = 0; tc < 4; tc++) {
            int c0 = tc * 16 + quad * 4;
            uint2 pk;
            pk.x = ((unsigned)f2bf(acc[tc][1] * di) << 16) | f2bf(acc[tc][0] * di);
            pk.y = ((unsigned)f2bf(acc[tc][3] * di) << 16) | f2bf(acc[tc][2] * di);
            *(uint2*)(hwb + (size_t)node * 64 + c0) = pk;
        }
    }
}

// agg16[d] = bf16(dinv[d]*(hwb[d] + sum_{s in N(d)} hwb[s])); BN stats on ROUNDED values.
// Wave = 4 rows x 16 lanes (2 sub-groups of 8); lane q holds ch 8q..8q+7 (uint4).
// R9: 4 gathers in flight per walker (was 2) — NO nt hints (R1's regression was
// the bundled nt, esp. nt-store on agg16). Accumulation order identical to R7.
#define ACC8(u) { a[0] += bflo(u.x); a[1] += bfhi(u.x); a[2] += bflo(u.y); a[3] += bfhi(u.y); \
                  a[4] += bflo(u.z); a[5] += bfhi(u.z); a[6] += bflo(u.w); a[7] += bfhi(u.w); }
__global__ void k_spmm(const int* __restrict__ rowptr, const int* __restrict__ ecol,
                       const unsigned short* __restrict__ hwb, const float* __restrict__ dinv,
                       unsigned short* __restrict__ agg16, double* __restrict__ sums) {
    int t = threadIdx.x;
    int w = t >> 6, l = t & 63;
    int r = l >> 4;          // row slot 0..3
    int sub = (l >> 3) & 1;  // edge sub-group
    int q = l & 7;           // channel quad
    const uint4* hw4 = (const uint4*)hwb;
    float ls[8], lq[8];
#pragma unroll
    for (int j = 0; j < 8; j++) { ls[j] = 0.f; lq[j] = 0.f; }
    for (int row0 = blockIdx.x * 16 + w * 4; row0 < NN; row0 += SPMM_BLOCKS * 16) {
        int row = row0 + r;
        bool valid = row < NN;
        int p0 = 0, p1 = 0;
        float a[8];
#pragma unroll
        for (int j = 0; j < 8; j++) a[j] = 0.f;
        if (valid) {
            p0 = rowptr[row];
            p1 = rowptr[row + 1];
            if (sub == 0) {
                uint4 sv = hw4[(size_t)row * 8 + q];
                ACC8(sv)
            }
        }
        int p = p0 + sub;
        for (; p + 6 < p1; p += 8) {   // 4 edges in flight
            int s0 = ecol[p], s1 = ecol[p + 2], s2 = ecol[p + 4], s3 = ecol[p + 6];
            uint4 u0 = hw4[(size_t)s0 * 8 + q];
            uint4 u1 = hw4[(size_t)s1 * 8 + q];
            uint4 u2 = hw4[(size_t)s2 * 8 + q];
            uint4 u3 = hw4[(size_t)s3 * 8 + q];
            ACC8(u0) ACC8(u1) ACC8(u2) ACC8(u3)
        }
        for (; p + 2 < p1; p += 4) {   // 2 edges in flight
            int s0 = ecol[p], s1 = ecol[p + 2];
            uint4 u0 = hw4[(size_t)s0 * 8 + q];
            uint4 u1 = hw4[(size_t)s1 * 8 + q];
            ACC8(u0) ACC8(u1)
        }
        if (p < p1) {
            int s0 = ecol[p];
            uint4 u0 = hw4[(size_t)s0 * 8 + q];
            ACC8(u0)
        }
#pragma unroll
        for (int j = 0; j < 8; j++) a[j] += __shfl_xor(a[j], 8, 64);
        if (valid && sub == 0) {
            float di = dinv[row];
            unsigned pk[4];
#pragma unroll
            for (int j = 0; j < 4; j++) {
                float v0 = a[2 * j] * di, v1 = a[2 * j + 1] * di;
                pk[j] = ((unsigned)f2bf(v1) << 16) | f2bf(v0);
            }
            *(uint4*)(agg16 + (size_t)row * 64 + 8 * q) = make_uint4(pk[0], pk[1], pk[2], pk[3]);
            // stats on the rounded (stored) values -> BN self-consistent
#pragma unroll
            for (int j = 0; j < 4; j++) {
                float v0 = bflo(pk[j]), v1 = bfhi(pk[j]);
                ls[2 * j] += v0; ls[2 * j + 1] += v1;
                lq[2 * j] = fmaf(v0, v0, lq[2 * j]);
                lq[2 * j + 1] = fmaf(v1, v1, lq[2 * j + 1]);
            }
        }
    }
#pragma unroll
    for (int j = 0; j < 8; j++) {
        ls[j] += __shfl_xor(ls[j], 16, 64); ls[j] += __shfl_xor(ls[j], 32, 64);
        lq[j] += __shfl_xor(lq[j], 16, 64); lq[j] += __shfl_xor(lq[j], 32, 64);
    }
    __shared__ float Ss[4][64], Sq[4][64];
    if (l < 8) {
#pragma unroll
        for (int j = 0; j < 8; j++) {
            Ss[w][8 * l + j] = ls[j];
            Sq[w][8 * l + j] = lq[j];
        }
    }
    __syncthreads();
    if (t < 64) {
        float a = Ss[0][t] + Ss[1][t] + Ss[2][t] + Ss[3][t];
        float b = Sq[0][t] + Sq[1][t] + Sq[2][t] + Sq[3][t];
        double* sh = sums + (blockIdx.x & 15) * 128;
        atomicAdd(&sh[t], (double)a);
        atomicAdd(&sh[64 + t], (double)b);
    }
}

// final-layer BN finalize (single launch after loop)
__global__ void k_finalize(const double* __restrict__ sums, const float* __restrict__ gamma,
                           const float* __restrict__ beta, float* __restrict__ ss) {
    int c = threadIdx.x;  // 64 threads
    double s = 0.0, q = 0.0;
#pragma unroll
    for (int k = 0; k < 16; k++) { s += sums[k * 128 + c]; q += sums[k * 128 + 64 + c]; }
    double mean = s / (double)NN;
    double var = q / (double)NN - mean * mean;
    float sc = gamma[c] * rsqrtf((float)var + BN_EPS);
    ss[c] = sc;
    ss[64 + c] = beta[c] - (float)mean * sc;
}

// final layer: xe16 += relu(agg16*scale + shift)  (in-place bf16 update)
__global__ void k_apply(const unsigned short* __restrict__ agg16, const float* __restrict__ ss,
                        unsigned short* __restrict__ xe16) {
    int i = blockIdx.x * blockDim.x + threadIdx.x;   // uint4 index, NN*8 total
    if (i < NN * 8) {
        int c0 = (i & 7) * 8;
        uint4 av = *(const uint4*)(agg16 + (size_t)i * 8);
        uint4 xv = *(const uint4*)(xe16 + (size_t)i * 8);
        unsigned as[4] = {av.x, av.y, av.z, av.w};
        unsigned xs[4] = {xv.x, xv.y, xv.z, xv.w};
#pragma unroll
        for (int j = 0; j < 4; j++) {
            int c = c0 + 2 * j;
            float v0 = bflo(xs[j]) + fmaxf(fmaf(bflo(as[j]), ss[c], ss[64 + c]), 0.f);
            float v1 = bfhi(xs[j]) + fmaxf(fmaf(bfhi(as[j]), ss[c + 1], ss[64 + c + 1]), 0.f);
            xs[j] = ((unsigned)f2bf(v1) << 16) | f2bf(v0);
        }
        *(uint4*)(xe16 + (size_t)i * 8) = make_uint4(xs[0], xs[1], xs[2], xs[3]);
    }
}

// out[e] = [xe16[s]; xe16[d]] @ fc_W + fc_b   (bf16 rows: 128B/row gather)
__global__ void k_out(const int* __restrict__ esrc, const int* __restrict__ edst,
                      const unsigned short* __restrict__ xe16, const float* __restrict__ fcW,
                      const float* __restrict__ fcb, float* __restrict__ out) {
    __shared__ float Ws[256];
    __shared__ float bs[2];
    int t = threadIdx.x;
    for (int i = t; i < 256; i += 256) Ws[i] = fcW[i];
    if (t < 2) bs[t] = fcb[t];
    __syncthreads();
    int e = blockIdx.x * blockDim.x + t;
    if (e < NEO) {
        int s = esrc[e], d = edst[e];
        const uint4* rs = (const uint4*)(xe16 + (size_t)s * 64);
        const uint4* rd = (const uint4*)(xe16 + (size_t)d * 64);
        float a0 = bs[0], a1 = bs[1];
#pragma unroll
        for (int i = 0; i < 8; i++) {
            uint4 v = rs[i];
            int c = i * 8;
            a0 += bflo(v.x) * Ws[(c + 0) * 2] + bfhi(v.x) * Ws[(c + 1) * 2] +
                  bflo(v.y) * Ws[(c + 2) * 2] + bfhi(v.y) * Ws[(c + 3) * 2] +
                  bflo(v.z) * Ws[(c + 4) * 2] + bfhi(v.z) * Ws[(c + 5) * 2] +
                  bflo(v.w) * Ws[(c + 6) * 2] + bfhi(v.w) * Ws[(c + 7) * 2];
            a1 += bflo(v.x) * Ws[(c + 0) * 2 + 1] + bfhi(v.x) * Ws[(c + 1) * 2 + 1] +
                  bflo(v.y) * Ws[(c + 2) * 2 + 1] + bfhi(v.y) * Ws[(c + 3) * 2 + 1] +
                  bflo(v.z) * Ws[(c + 4) * 2 + 1] + bfhi(v.z) * Ws[(c + 5) * 2 + 1] +
                  bflo(v.w) * Ws[(c + 6) * 2 + 1] + bfhi(v.w) * Ws[(c + 7) * 2 + 1];
        }
#pragma unroll
        for (int i = 0; i < 8; i++) {
            uint4 v = rd[i];
            int c = 64 + i * 8;
            a0 += bflo(v.x) * Ws[(c + 0) * 2] + bfhi(v.x) * Ws[(c + 1) * 2] +
                  bflo(v.y) * Ws[(c + 2) * 2] + bfhi(v.y) * Ws[(c + 3) * 2] +
                  bflo(v.z) * Ws[(c + 4) * 2] + bfhi(v.z) * Ws[(c + 5) * 2] +
                  bflo(v.w) * Ws[(c + 6) * 2] + bfhi(v.w) * Ws[(c + 7) * 2];
            a1 += bflo(v.x) * Ws[(c + 0) * 2 + 1] + bfhi(v.x) * Ws[(c + 1) * 2 + 1] +
                  bflo(v.y) * Ws[(c + 2) * 2 + 1] + bfhi(v.y) * Ws[(c + 3) * 2 + 1] +
                  bflo(v.z) * Ws[(c + 4) * 2 + 1] + bfhi(v.z) * Ws[(c + 5) * 2 + 1] +
                  bflo(v.w) * Ws[(c + 6) * 2 + 1] + bfhi(v.w) * Ws[(c + 7) * 2 + 1];
        }
        out[e * 2] = a0;
        out[e * 2 + 1] = a1;
    }
}

extern "C" void kernel_launch(void* const* d_in, const int* in_sizes, int n_in,
                              void* d_out, int out_size, void* d_ws, size_t ws_size,
                              hipStream_t stream) {
    const float* x      = (const float*)d_in[0];
    const int*   ei     = (const int*)d_in[1];
    const int*   eio    = (const int*)d_in[2];
    const float* W_emb  = (const float*)d_in[3];
    const float* b_emb  = (const float*)d_in[4];
    const float* conv_W = (const float*)d_in[5];
    // d_in[6] conv_b: cancels inside BN
    const float* bn_g   = (const float*)d_in[7];
    const float* bn_b   = (const float*)d_in[8];
    const float* fc_W   = (const float*)d_in[9];
    const float* fc_b   = (const float*)d_in[10];
    float* out = (float*)d_out;

    float* ws   = (float*)d_ws;
    int*   ecol = (int*)(ws + OFF_ECOL);
    unsigned short* xe16  = (unsigned short*)(ws + OFF_XE);
    unsigned short* agg16 = (unsigned short*)(ws + OFF_AGG);
    unsigned short* hwb   = (unsigned short*)(ws + OFF_HWB);
    // bucket scratch: XE/AGG regions are dead until k_embed / first k_spmm
    int* b1 = (int*)(ws + OFF_XE);
    int* b2 = (int*)(ws + OFF_AGG);

    float* od     = (float*)d_out;
    float* dinv   = od + OD_DINV;
    int*   rowptr = (int*)(od + OD_ROWPTR);
    float* ss     = od + OD_SS;
    double* sums  = (double*)(od + OD_SUMS);   // 2 x 2048 doubles, ping-pong
    int*   gcur   = (int*)(od + OD_GCUR);
    int*   scnt   = (int*)(od + OD_SCNT);
    int*   sbase  = (int*)(od + OD_SBASE);

    const int* src  = ei;
    const int* dst  = ei + NE;
    const int* esrc = eio;
    const int* edst = eio + NEO;

    // ---- atomic-free hierarchical CSR build ----
    (void)hipMemsetAsync(gcur, 0, 8 * sizeof(int), stream);
    (void)hipMemsetAsync(scnt, 0, 256 * sizeof(int), stream);
    k_bin<<<BIN_BLOCKS, 256, 0, stream>>>(src, dst, gcur, b1);
    k_bin2<<<8 * BIN2_BPG, 256, 0, stream>>>(gcur, b1, scnt, b2);
    k_scan256<<<1, 256, 0, stream>>>(scnt, sbase);
    k_build3<<<256, 256, 0, stream>>>(scnt, sbase, b2, ecol, rowptr, dinv);

    k_embed<<<(NN + 63) / 64, 256, 0, stream>>>(x, W_emb, b_emb, xe16);

    for (int l = 0; l < NL; l++) {
        double* sumsPrev = sums + ((l + 1) & 1) * 2048;
        double* sumsCur  = sums + (l & 1) * 2048;
        k_hw<<<(NN + 63) / 64, 256, 0, stream>>>(xe16, conv_W + l * 64 * 64, dinv, agg16,
                                                 bn_g + (l ? (l - 1) * 64 : 0),
                                                 bn_b + (l ? (l - 1) * 64 : 0),
                                                 sumsPrev, sumsCur, hwb, l > 0 ? 1 : 0);
        k_spmm<<<SPMM_BLOCKS, 256, 0, stream>>>(rowptr, ecol, hwb, dinv, agg16, sumsCur);
    }
    k_finalize<<<1, 64, 0, stream>>>(sums + ((NL - 1) & 1) * 2048,
                                     bn_g + (NL - 1) * 64, bn_b + (NL - 1) * 64, ss);
    k_apply<<<(NN * 8 + 255) / 256, 256, 0, stream>>>(agg16, ss, xe16);

    k_out<<<(NEO + 255) / 256, 256, 0, stream>>>(esrc, edst, xe16, fc_W, fc_b, out);
}